// Round 13
// baseline (659.293 us; speedup 1.0000x reference)
//
#include <hip/hip_runtime.h>
#include <math.h>

// Problem constants
constexpr int CVOC = 100;
constexpr int NCLS = 18;
constexpr int EE   = 512;   // word emb
constexpr int HHm  = 512;   // main GRU hidden
constexpr int CEc  = 128;   // char emb
constexpr int CHc  = 256;   // char GRU hidden
constexpr int BB   = 64;
constexpr int TT   = 64;
constexpr int CCh  = 16;    // chars per word
constexpr int NTOK = BB*TT;       // 4096
constexpr int G3C  = 3*CHc;       // 768
constexpr int G3H  = 3*HHm;       // 1536
constexpr int KIN  = EE + CHc;    // 768

typedef __attribute__((ext_vector_type(8))) short bf16x8;
typedef __attribute__((ext_vector_type(4))) float f32x4;

__device__ __forceinline__ float sigmoidf_(float x){ return 1.0f/(1.0f + __expf(-x)); }
__device__ __forceinline__ float tanhf_(float x){ return 1.0f - 2.0f/(__expf(2.0f*x) + 1.0f); }
__device__ __forceinline__ unsigned short f2bf(float x){
  unsigned int u = __float_as_uint(x);
  unsigned int r = (u + 0x7FFFu + ((u>>16)&1u)) >> 16;
  return (unsigned short)r;
}

// ---------------------------------------------------------------------------
// K1: char input-projection table U2[c][g] (f32, biases folded; +bhh for r,z)
__global__ void k_uchar(const float* __restrict__ cemb, const float* __restrict__ wih,
                        const float* __restrict__ bih, const float* __restrict__ bhh,
                        float* __restrict__ U2){
  const int c = blockIdx.x;
  const int g = threadIdx.x;
  const float* a = cemb + (size_t)c*CEc;
  const float* w = wih  + (size_t)g*CEc;
  float s = 0.f;
  for(int k=0;k<CEc;k++) s = fmaf(a[k], w[k], s);
  s += bih[g];
  if(g < 2*CHc) s += bhh[g];
  U2[(size_t)c*G3C + g] = s;
}

// ---------------------------------------------------------------------------
// generic transpose: in[R][C] -> out[C][R]
__global__ void k_transpose(const float* __restrict__ in, float* __restrict__ out,
                            int R, int C){
  int idx = blockIdx.x*blockDim.x + threadIdx.x;
  if(idx >= R*C) return;
  int k = idx / R;
  int j = idx % R;
  out[idx] = in[(size_t)j*C + k];
}

// ---------------------------------------------------------------------------
// f32 -> bf16 (RNE)
__global__ void k_w2bf(const float* __restrict__ in, unsigned short* __restrict__ out,
                       int n){
  int i = blockIdx.x*256 + threadIdx.x;
  if(i < n) out[i] = f2bf(in[i]);
}

// ---------------------------------------------------------------------------
// K2 v7: char GRU, bf16 MFMA, SPILL-FREE register budget.
// 256 blocks x 1024 thr (16 waves), 16 words/block.
// Wave wv owns cols [wv*16,+16) of all 3 gates. VGPR budget (cap 128):
//   wreg[2][8] (r,z resident)    = 64
//   wn[4] stream (n-gate, 2x4)   = 16 transient
//   acc[3] f32x4                 = 12
//   hfr[4]                       =  4
//   gather/epilogue temps        ~ 20
//   total ~115 -> NO spills, true 4 waves/SIMD.
// n-gate B-frag addresses are t-invariant -> L2-hot stream, TLP-hidden.
// chars preloaded once to LDS chs_all (kills per-step global chars chain).
// Math identical to v5/v6 (same MFMA ops, same order) -> absmax unchanged.
__global__ __launch_bounds__(1024, 1) void k_chargru(
    const int* __restrict__ chars, const float* __restrict__ U2,
    const unsigned short* __restrict__ Wb, const float* __restrict__ bhh,
    float* __restrict__ char_h){
  __shared__ unsigned short hb[16][264];   // 8.4KB bf16 h
  __shared__ float ux[2][16][772];         // 98.7KB gathered U2 rows (dbuf)
  __shared__ int chs_all[16][16];          // 1KB  [w][t]
  const int tid  = threadIdx.x;
  const int lane = tid & 63;
  const int wv   = tid >> 6;        // 0..15
  const int la   = lane & 15;
  const int lb   = lane >> 4;       // 0..3
  const int w0   = blockIdx.x * 16;
  const int c    = wv*16 + la;      // this thread's h-column (0..255)
  // ---- one-time: r,z B-tiles into registers (16 x bf16x8 = 64 VGPR) ----
  bf16x8 wreg[2][8];
  #pragma unroll
  for(int g=0; g<2; g++){
    const int gcol = g*CHc + c;
    #pragma unroll
    for(int ks=0; ks<8; ks++)
      wreg[g][ks] = *reinterpret_cast<const bf16x8*>(
          &Wb[(size_t)gcol*CHc + ks*32 + lb*8]);
  }
  const unsigned short* wnp = &Wb[(size_t)(2*CHc + c)*CHc + lb*8];  // n-gate row
  const float bhn = bhh[2*CHc + c];
  float hfr[4];                     // h f32: word lb*4+i, col c
  #pragma unroll
  for(int i=0;i<4;i++) hfr[i]=0.f;
  for(int f=tid; f<16*264; f+=1024) (&hb[0][0])[f] = 0;
  if(tid < 256) chs_all[tid>>4][tid&15] = chars[(size_t)(w0 + (tid>>4))*CCh + (tid&15)];
  // prologue: gather ux[0] for t=0 (3072 float4, 3 iters)
  #pragma unroll
  for(int i=0;i<3;i++){
    int idx = i*1024 + tid;
    int w = idx / 192;
    int c4 = idx - w*192;
    int ch = chars[(size_t)(w0+w)*CCh + 0];
    *reinterpret_cast<float4*>(&ux[0][w][c4*4]) =
        *reinterpret_cast<const float4*>(&U2[(size_t)ch*G3C + c4*4]);
  }
  __syncthreads();

  for(int t=0; t<CCh; t++){
    // ---- MFMA phase: r,z from regs; n streamed in 2 chunks of 4 ----
    f32x4 acc[3];
    #pragma unroll
    for(int g=0;g<3;g++) acc[g] = (f32x4){0.f,0.f,0.f,0.f};
    {
      bf16x8 wn[4];
      #pragma unroll
      for(int q=0;q<4;q++)
        wn[q] = *reinterpret_cast<const bf16x8*>(wnp + q*32);
      #pragma unroll
      for(int ks=0; ks<4; ks++){
        bf16x8 a = *reinterpret_cast<const bf16x8*>(&hb[la][ks*32 + lb*8]);
        acc[0] = __builtin_amdgcn_mfma_f32_16x16x32_bf16(a, wreg[0][ks], acc[0], 0,0,0);
        acc[1] = __builtin_amdgcn_mfma_f32_16x16x32_bf16(a, wreg[1][ks], acc[1], 0,0,0);
        acc[2] = __builtin_amdgcn_mfma_f32_16x16x32_bf16(a, wn[ks],      acc[2], 0,0,0);
      }
      #pragma unroll
      for(int q=0;q<4;q++)
        wn[q] = *reinterpret_cast<const bf16x8*>(wnp + (4+q)*32);
      #pragma unroll
      for(int ks=4; ks<8; ks++){
        bf16x8 a = *reinterpret_cast<const bf16x8*>(&hb[la][ks*32 + lb*8]);
        acc[0] = __builtin_amdgcn_mfma_f32_16x16x32_bf16(a, wreg[0][ks], acc[0], 0,0,0);
        acc[1] = __builtin_amdgcn_mfma_f32_16x16x32_bf16(a, wreg[1][ks], acc[1], 0,0,0);
        acc[2] = __builtin_amdgcn_mfma_f32_16x16x32_bf16(a, wn[ks-4],    acc[2], 0,0,0);
      }
    }
    __syncthreads();   // hb reads done; ux[t&1] visible
    // ---- gather ux for t+1 (chs from LDS; latency hides under epilogue) ----
    if(t < CCh-1){
      const int buf = (t+1)&1;
      #pragma unroll
      for(int i=0;i<3;i++){
        int idx = i*1024 + tid;
        int w = idx / 192;
        int c4 = idx - w*192;
        int ch = chs_all[w][t+1];
        *reinterpret_cast<float4*>(&ux[buf][w][c4*4]) =
            *reinterpret_cast<const float4*>(&U2[(size_t)ch*G3C + c4*4]);
      }
    }
    // ---- register epilogue (reads ux[t&1] from LDS) ----
    {
      const float* uxt = &ux[t&1][0][0];
      #pragma unroll
      for(int i=0;i<4;i++){
        const int w = lb*4 + i;
        const float* u = uxt + (size_t)w*772;
        float r = sigmoidf_(u[c]         + acc[0][i]);
        float z = sigmoidf_(u[CHc + c]   + acc[1][i]);
        float n = tanhf_   (u[2*CHc + c] + r*(acc[2][i] + bhn));
        float hn = (1.f - z)*n + z*hfr[i];
        hfr[i] = hn;
        hb[w][c] = f2bf(hn);
      }
    }
    __syncthreads();   // hb + ux[t+1] ready
  }
  // ---- writeout ----
  #pragma unroll
  for(int i=0;i<4;i++){
    const int w = lb*4 + i;
    char_h[(size_t)(w0+w)*CHc + c] = hfr[i];
  }
}

// ---------------------------------------------------------------------------
// K3: gx GEMM, f32 (unchanged). gx[token][g], bias folded (+bhh for r,z).
__global__ __launch_bounds__(256) void k_gxmain(
    const int* __restrict__ x, const float* __restrict__ wemb,
    const float* __restrict__ chh, const float* __restrict__ WihT,
    const float* __restrict__ bih, const float* __restrict__ bhh,
    float* __restrict__ gx){
  __shared__ float As[128][20];
  __shared__ float Bs[16][100];
  __shared__ int xs[128];
  const int tid = threadIdx.x;
  const int rb = blockIdx.x * 128;
  const int nb = blockIdx.y * 96;
  if(tid < 128) xs[tid] = x[rb + tid];
  const int tr = tid >> 4, tc = tid & 15;
  float acc[8][6];
  #pragma unroll
  for(int i=0;i<8;i++)
    #pragma unroll
    for(int j=0;j<6;j++) acc[i][j]=0.f;
  __syncthreads();
  for(int kb=0; kb<KIN; kb+=16){
    #pragma unroll
    for(int i=0;i<2;i++){
      int idx = i*256 + tid;
      int m = idx & 127, kq = idx >> 7;
      int k = kb + kq*4;
      float4 v;
      if(k < EE) v = *reinterpret_cast<const float4*>(&wemb[(size_t)xs[m]*EE + k]);
      else       v = *reinterpret_cast<const float4*>(&chh[(size_t)(rb+m)*CHc + (k-EE)]);
      *reinterpret_cast<float4*>(&As[m][kq*4]) = v;
    }
    #pragma unroll
    for(int i=0;i<2;i++){
      int idx = i*256 + tid;
      if(idx < 384){
        int k = idx / 24, n4 = (idx % 24)*4;
        *reinterpret_cast<float4*>(&Bs[k][n4]) =
            *reinterpret_cast<const float4*>(&WihT[(size_t)(kb+k)*G3H + nb + n4]);
      }
    }
    __syncthreads();
    #pragma unroll
    for(int k=0;k<16;k++){
      float a[8];
      #pragma unroll
      for(int i=0;i<4;i++){ a[i]=As[tr*4+i][k]; a[4+i]=As[64+tr*4+i][k]; }
      float2 b0 = *reinterpret_cast<const float2*>(&Bs[k][tc*2]);
      float2 b1 = *reinterpret_cast<const float2*>(&Bs[k][32+tc*2]);
      float2 b2 = *reinterpret_cast<const float2*>(&Bs[k][64+tc*2]);
      float b[6] = {b0.x,b0.y,b1.x,b1.y,b2.x,b2.y};
      #pragma unroll
      for(int i=0;i<8;i++)
        #pragma unroll
        for(int j=0;j<6;j++)
          acc[i][j] = fmaf(a[i], b[j], acc[i][j]);
    }
    __syncthreads();
  }
  #pragma unroll
  for(int i=0;i<8;i++){
    int row = rb + ((i<4) ? tr*4+i : 64 + tr*4 + (i-4));
    #pragma unroll
    for(int j=0;j<6;j++){
      int g = nb + (j>>1)*32 + tc*2 + (j&1);
      float v = acc[i][j] + bih[g] + (g < 2*HHm ? bhh[g] : 0.f);
      gx[(size_t)row*G3H + g] = v;
    }
  }
}

// ---------------------------------------------------------------------------
// K4 v6: main GRU, tag-packed h exchange + pipelined poll (unchanged, ~367us).
__global__ __launch_bounds__(512) void k_grumain(
    const float* __restrict__ Whh, const float* __restrict__ gx,
    const float* __restrict__ bhh, float* __restrict__ outh,
    unsigned long long* __restrict__ hx){
  __shared__ float hsh[8][516];      // 16.5KB
  __shared__ float red[3][8][16][9]; // 13.8KB
  const int tid  = threadIdx.x;
  const int lane = tid & 63;
  const int kw   = tid >> 6;
  const int jp   = lane & 15;
  const int bq   = lane >> 4;
  const int jb   = blockIdx.x & 31;
  const int bb   = blockIdx.x >> 5;
  const int jglob = jb*16 + jp;
  const int kbase = kw*64 + bq*16;
  float4 wreg[3][4];
  #pragma unroll
  for(int g=0; g<3; g++)
    #pragma unroll
    for(int q=0; q<4; q++)
      wreg[g][q] = *reinterpret_cast<const float4*>(
          &Whh[((size_t)g*HHm + jglob)*HHm + kbase + q*4]);
  const int fb  = tid >> 4;
  const int fj  = tid & 15;
  const int fjg = jb*16 + fj;
  const int fbg = bb*8 + fb;
  const float fbhn = bhh[2*HHm + fjg];

  for(int t=0; t<TT; t++){
    float gxr=0.f, gxz=0.f, gxn=0.f;
    if(tid < 128){
      const size_t tok = (size_t)fbg*TT + t;
      gxr = gx[tok*G3H +           fjg];
      gxz = gx[tok*G3H + HHm +     fjg];
      gxn = gx[tok*G3H + 2*HHm +   fjg];
    }
    if(t > 0){
      const unsigned int want = (unsigned int)t;
      const size_t sbase = (size_t)((t-1)&1)*BB*HHm;
      const unsigned long long* p[8];
      unsigned long long v[8];
      #pragma unroll
      for(int i=0;i<8;i++){
        int f = i*512 + tid;
        int b = f >> 9, k = f & 511;
        p[i] = &hx[sbase + (size_t)(bb*8+b)*HHm + k];
        v[i] = __hip_atomic_load(p[i], __ATOMIC_RELAXED, __HIP_MEMORY_SCOPE_AGENT);
      }
      #pragma unroll
      for(int i=0;i<8;i++){
        while((unsigned int)(v[i]>>32) != want){
          __builtin_amdgcn_s_sleep(1);
          v[i] = __hip_atomic_load(p[i], __ATOMIC_RELAXED, __HIP_MEMORY_SCOPE_AGENT);
        }
        int f = i*512 + tid;
        int b = f >> 9, k = f & 511;
        hsh[b][k] = __uint_as_float((unsigned int)v[i]);
      }
      __syncthreads();
      float aR[8], aZ[8], aN[8];
      #pragma unroll
      for(int b=0;b<8;b++){ aR[b]=0.f; aZ[b]=0.f; aN[b]=0.f; }
      #pragma unroll
      for(int b=0; b<8; b++){
        float4 h0 = *reinterpret_cast<const float4*>(&hsh[b][kbase+0]);
        float4 h1 = *reinterpret_cast<const float4*>(&hsh[b][kbase+4]);
        float4 h2 = *reinterpret_cast<const float4*>(&hsh[b][kbase+8]);
        float4 h3 = *reinterpret_cast<const float4*>(&hsh[b][kbase+12]);
        aR[b] = fmaf(h0.x,wreg[0][0].x, fmaf(h0.y,wreg[0][0].y, fmaf(h0.z,wreg[0][0].z, fmaf(h0.w,wreg[0][0].w, aR[b]))));
        aR[b] = fmaf(h1.x,wreg[0][1].x, fmaf(h1.y,wreg[0][1].y, fmaf(h1.z,wreg[0][1].z, fmaf(h1.w,wreg[0][1].w, aR[b]))));
        aR[b] = fmaf(h2.x,wreg[0][2].x, fmaf(h2.y,wreg[0][2].y, fmaf(h2.z,wreg[0][2].z, fmaf(h2.w,wreg[0][2].w, aR[b]))));
        aR[b] = fmaf(h3.x,wreg[0][3].x, fmaf(h3.y,wreg[0][3].y, fmaf(h3.z,wreg[0][3].z, fmaf(h3.w,wreg[0][3].w, aR[b]))));
        aZ[b] = fmaf(h0.x,wreg[1][0].x, fmaf(h0.y,wreg[1][0].y, fmaf(h0.z,wreg[1][0].z, fmaf(h0.w,wreg[1][0].w, aZ[b]))));
        aZ[b] = fmaf(h1.x,wreg[1][1].x, fmaf(h1.y,wreg[1][1].y, fmaf(h1.z,wreg[1][1].z, fmaf(h1.w,wreg[1][1].w, aZ[b]))));
        aZ[b] = fmaf(h2.x,wreg[1][2].x, fmaf(h2.y,wreg[1][2].y, fmaf(h2.z,wreg[1][2].z, fmaf(h2.w,wreg[1][2].w, aZ[b]))));
        aZ[b] = fmaf(h3.x,wreg[1][3].x, fmaf(h3.y,wreg[1][3].y, fmaf(h3.z,wreg[1][3].z, fmaf(h3.w,wreg[1][3].w, aZ[b]))));
        aN[b] = fmaf(h0.x,wreg[2][0].x, fmaf(h0.y,wreg[2][0].y, fmaf(h0.z,wreg[2][0].z, fmaf(h0.w,wreg[2][0].w, aN[b]))));
        aN[b] = fmaf(h1.x,wreg[2][1].x, fmaf(h1.y,wreg[2][1].y, fmaf(h1.z,wreg[2][1].z, fmaf(h1.w,wreg[2][1].w, aN[b]))));
        aN[b] = fmaf(h2.x,wreg[2][2].x, fmaf(h2.y,wreg[2][2].y, fmaf(h2.z,wreg[2][2].z, fmaf(h2.w,wreg[2][2].w, aN[b]))));
        aN[b] = fmaf(h3.x,wreg[2][3].x, fmaf(h3.y,wreg[2][3].y, fmaf(h3.z,wreg[2][3].z, fmaf(h3.w,wreg[2][3].w, aN[b]))));
      }
      #pragma unroll
      for(int b=0;b<8;b++){
        aR[b] += __shfl_xor(aR[b], 16, 64); aR[b] += __shfl_xor(aR[b], 32, 64);
        aZ[b] += __shfl_xor(aZ[b], 16, 64); aZ[b] += __shfl_xor(aZ[b], 32, 64);
        aN[b] += __shfl_xor(aN[b], 16, 64); aN[b] += __shfl_xor(aN[b], 32, 64);
      }
      #pragma unroll
      for(int i=0;i<2;i++){
        int b = bq*2 + i;
        red[0][b][jp][kw] = aR[b];
        red[1][b][jp][kw] = aZ[b];
        red[2][b][jp][kw] = aN[b];
      }
      __syncthreads();
    }
    if(tid < 128){
      float sR=0.f, sZ=0.f, sN=0.f, hold=0.f;
      if(t > 0){
        #pragma unroll
        for(int w=0; w<8; w++){
          sR += red[0][fb][fj][w];
          sZ += red[1][fb][fj][w];
          sN += red[2][fb][fj][w];
        }
        hold = hsh[fb][fjg];
      }
      float rg = sigmoidf_(gxr + sR);
      float zg = sigmoidf_(gxz + sZ);
      float ng = tanhf_   (gxn + rg*(sN + fbhn));
      float hnew = (1.f - zg)*ng + zg*hold;
      outh[((size_t)t*BB + fbg)*HHm + fjg] = hnew;   // f32 for k_cls
      unsigned long long pv = ((unsigned long long)(unsigned int)(t+1) << 32)
                              | (unsigned long long)__float_as_uint(hnew);
      __hip_atomic_store(&hx[(size_t)(t&1)*BB*HHm + (size_t)fbg*HHm + fjg], pv,
                         __ATOMIC_RELAXED, __HIP_MEMORY_SCOPE_AGENT);
    }
    __syncthreads();
  }
}

// ---------------------------------------------------------------------------
// K5: classifier. One block per time-step t; reads outh[t][b][j].
__global__ __launch_bounds__(256) void k_cls(
    const float* __restrict__ outh, const float* __restrict__ clsW,
    const float* __restrict__ clsb, float* __restrict__ out){
  __shared__ float wls[20*HHm];     // 40KB
  __shared__ float hch[64][129];    // 33KB
  const int tid = threadIdx.x;
  const int t = blockIdx.x;
  const int b = tid & 63;
  const int q = tid >> 6;
  const int c0 = q*5;
  for(int f = tid*4; f < 20*HHm; f += 1024){
    float4 v = make_float4(0.f,0.f,0.f,0.f);
    if(f < NCLS*HHm) v = *reinterpret_cast<const float4*>(&clsW[f]);
    *reinterpret_cast<float4*>(&wls[f]) = v;
  }
  float acc[5] = {0.f,0.f,0.f,0.f,0.f};
  for(int kc=0; kc<4; kc++){
    __syncthreads();
    for(int i=0;i<32;i++){
      int f = i*256 + tid;
      int b2 = f >> 7, kk = f & 127;
      hch[b2][kk] = outh[((size_t)t*BB + b2)*HHm + kc*128 + kk];
    }
    __syncthreads();
    for(int k=0;k<128;k++){
      float hv = hch[b][k];
      #pragma unroll
      for(int i=0;i<5;i++)
        acc[i] = fmaf(hv, wls[(size_t)(c0+i)*HHm + kc*128 + k], acc[i]);
    }
  }
  #pragma unroll
  for(int i=0;i<5;i++){
    int cls = c0 + i;
    if(cls < NCLS) out[((size_t)b*TT + t)*NCLS + cls] = acc[i] + clsb[cls];
  }
}

// ---------------------------------------------------------------------------
extern "C" void kernel_launch(void* const* d_in, const int* in_sizes, int n_in,
                              void* d_out, int out_size, void* d_ws, size_t ws_size,
                              hipStream_t stream){
  const int*   x     = (const int*)d_in[0];
  const int*   chars = (const int*)d_in[1];
  const float* wemb  = (const float*)d_in[2];
  const float* cemb  = (const float*)d_in[3];
  const float* cWih  = (const float*)d_in[4];
  const float* cWhh  = (const float*)d_in[5];
  const float* cbih  = (const float*)d_in[6];
  const float* cbhh  = (const float*)d_in[7];
  const float* gWih  = (const float*)d_in[8];
  const float* gWhh  = (const float*)d_in[9];
  const float* gbih  = (const float*)d_in[10];
  const float* gbhh  = (const float*)d_in[11];
  const float* clsW  = (const float*)d_in[12];
  const float* clsb  = (const float*)d_in[13];
  float* out = (float*)d_out;
  float* ws  = (float*)d_ws;

  // workspace layout (floats unless noted)
  float* U2    = ws;                   // 100*768    = 76800
  float* WihTm = U2 + 76800;           // 768*1536   = 1179648
  float* chh   = WihTm + 1179648;      // 4096*256   = 1048576
  float* gx    = chh + 1048576;        // 4096*1536  = 6291456   [token][g]
  float* outh  = gx + 6291456;         // 64*64*512  = 2097152   [t][b][j]
  unsigned long long* hx = (unsigned long long*)(outh + 2097152); // 2*64*512 u64
  unsigned short* Wb = (unsigned short*)(hx + 2*BB*HHm);          // 768*256 bf16

  k_uchar<<<CVOC, G3C, 0, stream>>>(cemb, cWih, cbih, cbhh, U2);
  k_w2bf<<<(G3C*CHc + 255)/256, 256, 0, stream>>>(cWhh, Wb, G3C*CHc);
  k_transpose<<<(G3H*KIN + 255)/256, 256, 0, stream>>>(gWih, WihTm, G3H, KIN);
  k_chargru<<<NTOK/16, 1024, 0, stream>>>(chars, U2, Wb, cbhh, chh);
  k_gxmain<<<dim3(NTOK/128, G3H/96), 256, 0, stream>>>(x, wemb, chh, WihTm, gbih, gbhh, gx);
  k_grumain<<<256, 512, 0, stream>>>(gWhh, gx, gbhh, outh, hx);
  k_cls<<<TT, 256, 0, stream>>>(outh, clsW, clsb, out);
}

// Round 14
// 616.607 us; speedup vs baseline: 1.0692x; 1.0692x over previous
//
#include <hip/hip_runtime.h>
#include <math.h>

// Problem constants
constexpr int CVOC = 100;
constexpr int NCLS = 18;
constexpr int EE   = 512;   // word emb
constexpr int HHm  = 512;   // main GRU hidden
constexpr int CEc  = 128;   // char emb
constexpr int CHc  = 256;   // char GRU hidden
constexpr int BB   = 64;
constexpr int TT   = 64;
constexpr int CCh  = 16;    // chars per word
constexpr int NTOK = BB*TT;       // 4096
constexpr int G3C  = 3*CHc;       // 768
constexpr int G3H  = 3*HHm;       // 1536
constexpr int KIN  = EE + CHc;    // 768

typedef __attribute__((ext_vector_type(8))) short bf16x8;
typedef __attribute__((ext_vector_type(4))) float f32x4;

__device__ __forceinline__ float sigmoidf_(float x){ return 1.0f/(1.0f + __expf(-x)); }
__device__ __forceinline__ float tanhf_(float x){ return 1.0f - 2.0f/(__expf(2.0f*x) + 1.0f); }
__device__ __forceinline__ unsigned short f2bf(float x){
  unsigned int u = __float_as_uint(x);
  unsigned int r = (u + 0x7FFFu + ((u>>16)&1u)) >> 16;
  return (unsigned short)r;
}

// ---------------------------------------------------------------------------
// K1: char input-projection table U2[c][g] (f32, biases folded; +bhh for r,z)
__global__ void k_uchar(const float* __restrict__ cemb, const float* __restrict__ wih,
                        const float* __restrict__ bih, const float* __restrict__ bhh,
                        float* __restrict__ U2){
  const int c = blockIdx.x;
  const int g = threadIdx.x;
  const float* a = cemb + (size_t)c*CEc;
  const float* w = wih  + (size_t)g*CEc;
  float s = 0.f;
  for(int k=0;k<CEc;k++) s = fmaf(a[k], w[k], s);
  s += bih[g];
  if(g < 2*CHc) s += bhh[g];
  U2[(size_t)c*G3C + g] = s;
}

// ---------------------------------------------------------------------------
// generic transpose: in[R][C] -> out[C][R]
__global__ void k_transpose(const float* __restrict__ in, float* __restrict__ out,
                            int R, int C){
  int idx = blockIdx.x*blockDim.x + threadIdx.x;
  if(idx >= R*C) return;
  int k = idx / R;
  int j = idx % R;
  out[idx] = in[(size_t)j*C + k];
}

// ---------------------------------------------------------------------------
// f32 -> bf16 (RNE)
__global__ void k_w2bf(const float* __restrict__ in, unsigned short* __restrict__ out,
                       int n){
  int i = blockIdx.x*256 + threadIdx.x;
  if(i < n) out[i] = f2bf(in[i]);
}

// ---------------------------------------------------------------------------
// K2 v8: char GRU, bf16 MFMA, NO ux staging — direct per-thread U2 loads.
// 256 blocks x 1024 thr (16 waves), 16 words/block; wave wv owns cols
// [wv*16,+16) of all 3 gates. Each thread needs only 12 f32/step from the
// L2-resident U2 table (307KB): issued at STEP START (depend only on chs),
// consumed in the epilogue after MFMA+barrier (~500cyc covering latency).
// Removes: 3 VMEM float4 + 12 LDS writes + LDS reads + vmcnt/barrier
// coupling + 99KB LDS of the old gather. Weights: r,z register-resident
// (64 VGPR), n-gate streamed (t-invariant addresses, L2-hot). VGPR ~123.
// Math identical to v5/v6/v7 -> absmax unchanged.
__global__ __launch_bounds__(1024, 1) void k_chargru(
    const int* __restrict__ chars, const float* __restrict__ U2,
    const unsigned short* __restrict__ Wb, const float* __restrict__ bhh,
    float* __restrict__ char_h){
  __shared__ unsigned short hb[16][280];   // 9KB bf16 h (stride 560B, 16B-aligned)
  __shared__ int chs_all[16][16];          // 1KB [w][t]
  const int tid  = threadIdx.x;
  const int lane = tid & 63;
  const int wv   = tid >> 6;        // 0..15
  const int la   = lane & 15;
  const int lb   = lane >> 4;       // 0..3
  const int w0   = blockIdx.x * 16;
  const int c    = wv*16 + la;      // this thread's h-column (0..255)
  // ---- one-time: r,z B-tiles into registers (16 x bf16x8 = 64 VGPR) ----
  bf16x8 wreg[2][8];
  #pragma unroll
  for(int g=0; g<2; g++){
    const int gcol = g*CHc + c;
    #pragma unroll
    for(int ks=0; ks<8; ks++)
      wreg[g][ks] = *reinterpret_cast<const bf16x8*>(
          &Wb[(size_t)gcol*CHc + ks*32 + lb*8]);
  }
  const unsigned short* wnp = &Wb[(size_t)(2*CHc + c)*CHc + lb*8];  // n-gate row
  const float bhn = bhh[2*CHc + c];
  float hfr[4];                     // h f32: word lb*4+i, col c
  #pragma unroll
  for(int i=0;i<4;i++) hfr[i]=0.f;
  for(int f=tid; f<16*280; f+=1024) (&hb[0][0])[f] = 0;
  if(tid < 256) chs_all[tid>>4][tid&15] = chars[(size_t)(w0 + (tid>>4))*CCh + (tid&15)];
  __syncthreads();

  for(int t=0; t<CCh; t++){
    // ---- issue this step's 12 U2 loads (independent of h; consumed post-MFMA)
    float u2v[4][3];
    #pragma unroll
    for(int i=0;i<4;i++){
      const int ch = chs_all[lb*4 + i][t];
      const float* urow = U2 + (size_t)ch*G3C;
      u2v[i][0] = urow[c];
      u2v[i][1] = urow[CHc + c];
      u2v[i][2] = urow[2*CHc + c];
    }
    // ---- MFMA phase: r,z from regs; n streamed in 2 chunks of 4 ----
    f32x4 acc[3];
    #pragma unroll
    for(int g=0;g<3;g++) acc[g] = (f32x4){0.f,0.f,0.f,0.f};
    {
      bf16x8 wn[4];
      #pragma unroll
      for(int q=0;q<4;q++)
        wn[q] = *reinterpret_cast<const bf16x8*>(wnp + q*32);
      #pragma unroll
      for(int ks=0; ks<4; ks++){
        bf16x8 a = *reinterpret_cast<const bf16x8*>(&hb[la][ks*32 + lb*8]);
        acc[0] = __builtin_amdgcn_mfma_f32_16x16x32_bf16(a, wreg[0][ks], acc[0], 0,0,0);
        acc[1] = __builtin_amdgcn_mfma_f32_16x16x32_bf16(a, wreg[1][ks], acc[1], 0,0,0);
        acc[2] = __builtin_amdgcn_mfma_f32_16x16x32_bf16(a, wn[ks],      acc[2], 0,0,0);
      }
      #pragma unroll
      for(int q=0;q<4;q++)
        wn[q] = *reinterpret_cast<const bf16x8*>(wnp + (4+q)*32);
      #pragma unroll
      for(int ks=4; ks<8; ks++){
        bf16x8 a = *reinterpret_cast<const bf16x8*>(&hb[la][ks*32 + lb*8]);
        acc[0] = __builtin_amdgcn_mfma_f32_16x16x32_bf16(a, wreg[0][ks], acc[0], 0,0,0);
        acc[1] = __builtin_amdgcn_mfma_f32_16x16x32_bf16(a, wreg[1][ks], acc[1], 0,0,0);
        acc[2] = __builtin_amdgcn_mfma_f32_16x16x32_bf16(a, wn[ks-4],    acc[2], 0,0,0);
      }
    }
    __syncthreads();   // hb reads done (epilogue below overwrites hb)
    // ---- register epilogue (u2v long in flight; identical math) ----
    #pragma unroll
    for(int i=0;i<4;i++){
      const int w = lb*4 + i;
      float r = sigmoidf_(u2v[i][0] + acc[0][i]);
      float z = sigmoidf_(u2v[i][1] + acc[1][i]);
      float n = tanhf_   (u2v[i][2] + r*(acc[2][i] + bhn));
      float hn = (1.f - z)*n + z*hfr[i];
      hfr[i] = hn;
      hb[w][c] = f2bf(hn);
    }
    __syncthreads();   // hb ready for next step's MFMA
  }
  // ---- writeout ----
  #pragma unroll
  for(int i=0;i<4;i++){
    const int w = lb*4 + i;
    char_h[(size_t)(w0+w)*CHc + c] = hfr[i];
  }
}

// ---------------------------------------------------------------------------
// K3: gx GEMM, f32 (unchanged). gx[token][g], bias folded (+bhh for r,z).
__global__ __launch_bounds__(256) void k_gxmain(
    const int* __restrict__ x, const float* __restrict__ wemb,
    const float* __restrict__ chh, const float* __restrict__ WihT,
    const float* __restrict__ bih, const float* __restrict__ bhh,
    float* __restrict__ gx){
  __shared__ float As[128][20];
  __shared__ float Bs[16][100];
  __shared__ int xs[128];
  const int tid = threadIdx.x;
  const int rb = blockIdx.x * 128;
  const int nb = blockIdx.y * 96;
  if(tid < 128) xs[tid] = x[rb + tid];
  const int tr = tid >> 4, tc = tid & 15;
  float acc[8][6];
  #pragma unroll
  for(int i=0;i<8;i++)
    #pragma unroll
    for(int j=0;j<6;j++) acc[i][j]=0.f;
  __syncthreads();
  for(int kb=0; kb<KIN; kb+=16){
    #pragma unroll
    for(int i=0;i<2;i++){
      int idx = i*256 + tid;
      int m = idx & 127, kq = idx >> 7;
      int k = kb + kq*4;
      float4 v;
      if(k < EE) v = *reinterpret_cast<const float4*>(&wemb[(size_t)xs[m]*EE + k]);
      else       v = *reinterpret_cast<const float4*>(&chh[(size_t)(rb+m)*CHc + (k-EE)]);
      *reinterpret_cast<float4*>(&As[m][kq*4]) = v;
    }
    #pragma unroll
    for(int i=0;i<2;i++){
      int idx = i*256 + tid;
      if(idx < 384){
        int k = idx / 24, n4 = (idx % 24)*4;
        *reinterpret_cast<float4*>(&Bs[k][n4]) =
            *reinterpret_cast<const float4*>(&WihT[(size_t)(kb+k)*G3H + nb + n4]);
      }
    }
    __syncthreads();
    #pragma unroll
    for(int k=0;k<16;k++){
      float a[8];
      #pragma unroll
      for(int i=0;i<4;i++){ a[i]=As[tr*4+i][k]; a[4+i]=As[64+tr*4+i][k]; }
      float2 b0 = *reinterpret_cast<const float2*>(&Bs[k][tc*2]);
      float2 b1 = *reinterpret_cast<const float2*>(&Bs[k][32+tc*2]);
      float2 b2 = *reinterpret_cast<const float2*>(&Bs[k][64+tc*2]);
      float b[6] = {b0.x,b0.y,b1.x,b1.y,b2.x,b2.y};
      #pragma unroll
      for(int i=0;i<8;i++)
        #pragma unroll
        for(int j=0;j<6;j++)
          acc[i][j] = fmaf(a[i], b[j], acc[i][j]);
    }
    __syncthreads();
  }
  #pragma unroll
  for(int i=0;i<8;i++){
    int row = rb + ((i<4) ? tr*4+i : 64 + tr*4 + (i-4));
    #pragma unroll
    for(int j=0;j<6;j++){
      int g = nb + (j>>1)*32 + tc*2 + (j&1);
      float v = acc[i][j] + bih[g] + (g < 2*HHm ? bhh[g] : 0.f);
      gx[(size_t)row*G3H + g] = v;
    }
  }
}

// ---------------------------------------------------------------------------
// K4 v6: main GRU, tag-packed h exchange + pipelined poll (unchanged, ~367us).
__global__ __launch_bounds__(512) void k_grumain(
    const float* __restrict__ Whh, const float* __restrict__ gx,
    const float* __restrict__ bhh, float* __restrict__ outh,
    unsigned long long* __restrict__ hx){
  __shared__ float hsh[8][516];      // 16.5KB
  __shared__ float red[3][8][16][9]; // 13.8KB
  const int tid  = threadIdx.x;
  const int lane = tid & 63;
  const int kw   = tid >> 6;
  const int jp   = lane & 15;
  const int bq   = lane >> 4;
  const int jb   = blockIdx.x & 31;
  const int bb   = blockIdx.x >> 5;
  const int jglob = jb*16 + jp;
  const int kbase = kw*64 + bq*16;
  float4 wreg[3][4];
  #pragma unroll
  for(int g=0; g<3; g++)
    #pragma unroll
    for(int q=0; q<4; q++)
      wreg[g][q] = *reinterpret_cast<const float4*>(
          &Whh[((size_t)g*HHm + jglob)*HHm + kbase + q*4]);
  const int fb  = tid >> 4;
  const int fj  = tid & 15;
  const int fjg = jb*16 + fj;
  const int fbg = bb*8 + fb;
  const float fbhn = bhh[2*HHm + fjg];

  for(int t=0; t<TT; t++){
    float gxr=0.f, gxz=0.f, gxn=0.f;
    if(tid < 128){
      const size_t tok = (size_t)fbg*TT + t;
      gxr = gx[tok*G3H +           fjg];
      gxz = gx[tok*G3H + HHm +     fjg];
      gxn = gx[tok*G3H + 2*HHm +   fjg];
    }
    if(t > 0){
      const unsigned int want = (unsigned int)t;
      const size_t sbase = (size_t)((t-1)&1)*BB*HHm;
      const unsigned long long* p[8];
      unsigned long long v[8];
      #pragma unroll
      for(int i=0;i<8;i++){
        int f = i*512 + tid;
        int b = f >> 9, k = f & 511;
        p[i] = &hx[sbase + (size_t)(bb*8+b)*HHm + k];
        v[i] = __hip_atomic_load(p[i], __ATOMIC_RELAXED, __HIP_MEMORY_SCOPE_AGENT);
      }
      #pragma unroll
      for(int i=0;i<8;i++){
        while((unsigned int)(v[i]>>32) != want){
          __builtin_amdgcn_s_sleep(1);
          v[i] = __hip_atomic_load(p[i], __ATOMIC_RELAXED, __HIP_MEMORY_SCOPE_AGENT);
        }
        int f = i*512 + tid;
        int b = f >> 9, k = f & 511;
        hsh[b][k] = __uint_as_float((unsigned int)v[i]);
      }
      __syncthreads();
      float aR[8], aZ[8], aN[8];
      #pragma unroll
      for(int b=0;b<8;b++){ aR[b]=0.f; aZ[b]=0.f; aN[b]=0.f; }
      #pragma unroll
      for(int b=0; b<8; b++){
        float4 h0 = *reinterpret_cast<const float4*>(&hsh[b][kbase+0]);
        float4 h1 = *reinterpret_cast<const float4*>(&hsh[b][kbase+4]);
        float4 h2 = *reinterpret_cast<const float4*>(&hsh[b][kbase+8]);
        float4 h3 = *reinterpret_cast<const float4*>(&hsh[b][kbase+12]);
        aR[b] = fmaf(h0.x,wreg[0][0].x, fmaf(h0.y,wreg[0][0].y, fmaf(h0.z,wreg[0][0].z, fmaf(h0.w,wreg[0][0].w, aR[b]))));
        aR[b] = fmaf(h1.x,wreg[0][1].x, fmaf(h1.y,wreg[0][1].y, fmaf(h1.z,wreg[0][1].z, fmaf(h1.w,wreg[0][1].w, aR[b]))));
        aR[b] = fmaf(h2.x,wreg[0][2].x, fmaf(h2.y,wreg[0][2].y, fmaf(h2.z,wreg[0][2].z, fmaf(h2.w,wreg[0][2].w, aR[b]))));
        aR[b] = fmaf(h3.x,wreg[0][3].x, fmaf(h3.y,wreg[0][3].y, fmaf(h3.z,wreg[0][3].z, fmaf(h3.w,wreg[0][3].w, aR[b]))));
        aZ[b] = fmaf(h0.x,wreg[1][0].x, fmaf(h0.y,wreg[1][0].y, fmaf(h0.z,wreg[1][0].z, fmaf(h0.w,wreg[1][0].w, aZ[b]))));
        aZ[b] = fmaf(h1.x,wreg[1][1].x, fmaf(h1.y,wreg[1][1].y, fmaf(h1.z,wreg[1][1].z, fmaf(h1.w,wreg[1][1].w, aZ[b]))));
        aZ[b] = fmaf(h2.x,wreg[1][2].x, fmaf(h2.y,wreg[1][2].y, fmaf(h2.z,wreg[1][2].z, fmaf(h2.w,wreg[1][2].w, aZ[b]))));
        aZ[b] = fmaf(h3.x,wreg[1][3].x, fmaf(h3.y,wreg[1][3].y, fmaf(h3.z,wreg[1][3].z, fmaf(h3.w,wreg[1][3].w, aZ[b]))));
        aN[b] = fmaf(h0.x,wreg[2][0].x, fmaf(h0.y,wreg[2][0].y, fmaf(h0.z,wreg[2][0].z, fmaf(h0.w,wreg[2][0].w, aN[b]))));
        aN[b] = fmaf(h1.x,wreg[2][1].x, fmaf(h1.y,wreg[2][1].y, fmaf(h1.z,wreg[2][1].z, fmaf(h1.w,wreg[2][1].w, aN[b]))));
        aN[b] = fmaf(h2.x,wreg[2][2].x, fmaf(h2.y,wreg[2][2].y, fmaf(h2.z,wreg[2][2].z, fmaf(h2.w,wreg[2][2].w, aN[b]))));
        aN[b] = fmaf(h3.x,wreg[2][3].x, fmaf(h3.y,wreg[2][3].y, fmaf(h3.z,wreg[2][3].z, fmaf(h3.w,wreg[2][3].w, aN[b]))));
      }
      #pragma unroll
      for(int b=0;b<8;b++){
        aR[b] += __shfl_xor(aR[b], 16, 64); aR[b] += __shfl_xor(aR[b], 32, 64);
        aZ[b] += __shfl_xor(aZ[b], 16, 64); aZ[b] += __shfl_xor(aZ[b], 32, 64);
        aN[b] += __shfl_xor(aN[b], 16, 64); aN[b] += __shfl_xor(aN[b], 32, 64);
      }
      #pragma unroll
      for(int i=0;i<2;i++){
        int b = bq*2 + i;
        red[0][b][jp][kw] = aR[b];
        red[1][b][jp][kw] = aZ[b];
        red[2][b][jp][kw] = aN[b];
      }
      __syncthreads();
    }
    if(tid < 128){
      float sR=0.f, sZ=0.f, sN=0.f, hold=0.f;
      if(t > 0){
        #pragma unroll
        for(int w=0; w<8; w++){
          sR += red[0][fb][fj][w];
          sZ += red[1][fb][fj][w];
          sN += red[2][fb][fj][w];
        }
        hold = hsh[fb][fjg];
      }
      float rg = sigmoidf_(gxr + sR);
      float zg = sigmoidf_(gxz + sZ);
      float ng = tanhf_   (gxn + rg*(sN + fbhn));
      float hnew = (1.f - zg)*ng + zg*hold;
      outh[((size_t)t*BB + fbg)*HHm + fjg] = hnew;   // f32 for k_cls
      unsigned long long pv = ((unsigned long long)(unsigned int)(t+1) << 32)
                              | (unsigned long long)__float_as_uint(hnew);
      __hip_atomic_store(&hx[(size_t)(t&1)*BB*HHm + (size_t)fbg*HHm + fjg], pv,
                         __ATOMIC_RELAXED, __HIP_MEMORY_SCOPE_AGENT);
    }
    __syncthreads();
  }
}

// ---------------------------------------------------------------------------
// K5: classifier. One block per time-step t; reads outh[t][b][j].
__global__ __launch_bounds__(256) void k_cls(
    const float* __restrict__ outh, const float* __restrict__ clsW,
    const float* __restrict__ clsb, float* __restrict__ out){
  __shared__ float wls[20*HHm];     // 40KB
  __shared__ float hch[64][129];    // 33KB
  const int tid = threadIdx.x;
  const int t = blockIdx.x;
  const int b = tid & 63;
  const int q = tid >> 6;
  const int c0 = q*5;
  for(int f = tid*4; f < 20*HHm; f += 1024){
    float4 v = make_float4(0.f,0.f,0.f,0.f);
    if(f < NCLS*HHm) v = *reinterpret_cast<const float4*>(&clsW[f]);
    *reinterpret_cast<float4*>(&wls[f]) = v;
  }
  float acc[5] = {0.f,0.f,0.f,0.f,0.f};
  for(int kc=0; kc<4; kc++){
    __syncthreads();
    for(int i=0;i<32;i++){
      int f = i*256 + tid;
      int b2 = f >> 7, kk = f & 127;
      hch[b2][kk] = outh[((size_t)t*BB + b2)*HHm + kc*128 + kk];
    }
    __syncthreads();
    for(int k=0;k<128;k++){
      float hv = hch[b][k];
      #pragma unroll
      for(int i=0;i<5;i++)
        acc[i] = fmaf(hv, wls[(size_t)(c0+i)*HHm + kc*128 + k], acc[i]);
    }
  }
  #pragma unroll
  for(int i=0;i<5;i++){
    int cls = c0 + i;
    if(cls < NCLS) out[((size_t)b*TT + t)*NCLS + cls] = acc[i] + clsb[cls];
  }
}

// ---------------------------------------------------------------------------
extern "C" void kernel_launch(void* const* d_in, const int* in_sizes, int n_in,
                              void* d_out, int out_size, void* d_ws, size_t ws_size,
                              hipStream_t stream){
  const int*   x     = (const int*)d_in[0];
  const int*   chars = (const int*)d_in[1];
  const float* wemb  = (const float*)d_in[2];
  const float* cemb  = (const float*)d_in[3];
  const float* cWih  = (const float*)d_in[4];
  const float* cWhh  = (const float*)d_in[5];
  const float* cbih  = (const float*)d_in[6];
  const float* cbhh  = (const float*)d_in[7];
  const float* gWih  = (const float*)d_in[8];
  const float* gWhh  = (const float*)d_in[9];
  const float* gbih  = (const float*)d_in[10];
  const float* gbhh  = (const float*)d_in[11];
  const float* clsW  = (const float*)d_in[12];
  const float* clsb  = (const float*)d_in[13];
  float* out = (float*)d_out;
  float* ws  = (float*)d_ws;

  // workspace layout (floats unless noted)
  float* U2    = ws;                   // 100*768    = 76800
  float* WihTm = U2 + 76800;           // 768*1536   = 1179648
  float* chh   = WihTm + 1179648;      // 4096*256   = 1048576
  float* gx    = chh + 1048576;        // 4096*1536  = 6291456   [token][g]
  float* outh  = gx + 6291456;         // 64*64*512  = 2097152   [t][b][j]
  unsigned long long* hx = (unsigned long long*)(outh + 2097152); // 2*64*512 u64
  unsigned short* Wb = (unsigned short*)(hx + 2*BB*HHm);          // 768*256 bf16

  k_uchar<<<CVOC, G3C, 0, stream>>>(cemb, cWih, cbih, cbhh, U2);
  k_w2bf<<<(G3C*CHc + 255)/256, 256, 0, stream>>>(cWhh, Wb, G3C*CHc);
  k_transpose<<<(G3H*KIN + 255)/256, 256, 0, stream>>>(gWih, WihTm, G3H, KIN);
  k_chargru<<<NTOK/16, 1024, 0, stream>>>(chars, U2, Wb, cbhh, chh);
  k_gxmain<<<dim3(NTOK/128, G3H/96), 256, 0, stream>>>(x, wemb, chh, WihTm, gbih, gbhh, gx);
  k_grumain<<<256, 512, 0, stream>>>(gWhh, gx, gbhh, outh, hx);
  k_cls<<<TT, 256, 0, stream>>>(outh, clsW, clsb, out);
}